// Round 12
// baseline (308.962 us; speedup 1.0000x reference)
//
#include <hip/hip_runtime.h>
#include <math.h>

#define N_NODES 50000
#define N_EDGES 800000
#define EP (N_EDGES + N_NODES)   // edges + self loops
#define IN_DIM 128
#define HID 64
#define HEADS 2
#define OUT_DIM 2
#define N_GRAPHS 512
#define NEG_SLOPE 0.2f
#define NB_SCAN 196              // ceil(50000/256)
#define G_GEMM1 1563             // ceil(50000/32) blocks of 4 waves x 8 nodes
#define G_HIST 3321              // ceil(850000/256)

typedef unsigned int uint;
typedef unsigned short ushort;

// round-to-nearest-even f32 -> bf16
__device__ __forceinline__ ushort f2bf(float f) {
    uint u = __float_as_uint(f);
    u += 0x7fffu + ((u >> 16) & 1u);
    return (ushort)(u >> 16);
}
__device__ __forceinline__ float bf_lo(uint u) { return __uint_as_float(u << 16); }
__device__ __forceinline__ float bf_hi(uint u) { return __uint_as_float(u & 0xffff0000u); }

// ---------- fused: layer-1 GEMM+alphas (blocks [0,G_GEMM1)) + histogram ----------
__global__ void fused_gemm1_hist(const float* __restrict__ X, const float* __restrict__ W,
                                 ushort* __restrict__ Y,
                                 const float* __restrict__ a_src, const float* __restrict__ a_dst,
                                 float* __restrict__ as, float* __restrict__ ad,
                                 const int* __restrict__ ei, int* __restrict__ cnt,
                                 int* __restrict__ erank) {
    if (blockIdx.x >= G_GEMM1) {
        int i = (blockIdx.x - G_GEMM1) * 256 + threadIdx.x;
        if (i < EP) {
            int d = (i < N_EDGES) ? ei[N_EDGES + i] : (i - N_EDGES);
            erank[i] = atomicAdd(&cnt[d], 1);
        }
        return;
    }
    __shared__ float xs[32][128];
    const int wave = threadIdx.x >> 6;
    const int lane = threadIdx.x & 63;
    const int base = blockIdx.x * 32 + wave * 8;
    const float4* X4 = (const float4*)X;
    for (int idx = lane; idx < 8 * 32; idx += 64) {
        int r = idx >> 5, c = idx & 31;
        int n = base + r;
        float4 v = (n < N_NODES) ? X4[(size_t)n * 32 + c] : make_float4(0.f, 0.f, 0.f, 0.f);
        ((float4*)xs[wave * 8 + r])[c] = v;
    }
    __syncthreads();

    float acc0[8], acc1[8];
#pragma unroll
    for (int i = 0; i < 8; i++) { acc0[i] = 0.f; acc1[i] = 0.f; }
    for (int k = 0; k < 128; k += 4) {
        float wA[4], wB[4];
#pragma unroll
        for (int kk = 0; kk < 4; kk++) {
            wA[kk] = W[(size_t)(k + kk) * 128 + lane];
            wB[kk] = W[(size_t)(k + kk) * 128 + 64 + lane];
        }
#pragma unroll
        for (int i = 0; i < 8; i++) {
            float4 xv = *(const float4*)&xs[wave * 8 + i][k];
            acc0[i] = fmaf(xv.x, wA[0], acc0[i]); acc1[i] = fmaf(xv.x, wB[0], acc1[i]);
            acc0[i] = fmaf(xv.y, wA[1], acc0[i]); acc1[i] = fmaf(xv.y, wB[1], acc1[i]);
            acc0[i] = fmaf(xv.z, wA[2], acc0[i]); acc1[i] = fmaf(xv.z, wB[2], acc1[i]);
            acc0[i] = fmaf(xv.w, wA[3], acc0[i]); acc1[i] = fmaf(xv.w, wB[3], acc1[i]);
        }
    }

    const float asv0 = a_src[lane],      adv0 = a_dst[lane];
    const float asv1 = a_src[64 + lane], adv1 = a_dst[64 + lane];
#pragma unroll
    for (int i = 0; i < 8; i++) {
        int n = base + i;
        if (n >= N_NODES) continue;
        Y[(size_t)n * 128 + lane]      = f2bf(acc0[i]);
        Y[(size_t)n * 128 + 64 + lane] = f2bf(acc1[i]);
        float s0 = acc0[i] * asv0, d0 = acc0[i] * adv0;
        float s1 = acc1[i] * asv1, d1 = acc1[i] * adv1;
#pragma unroll
        for (int off = 32; off; off >>= 1) {
            s0 += __shfl_xor(s0, off);
            d0 += __shfl_xor(d0, off);
            s1 += __shfl_xor(s1, off);
            d1 += __shfl_xor(d1, off);
        }
        if (lane == 0) {
            as[(size_t)n * 2 + 0] = s0; as[(size_t)n * 2 + 1] = s1;
            ad[(size_t)n * 2 + 0] = d0; ad[(size_t)n * 2 + 1] = d1;
        }
    }
}

__global__ void partial_kernel(const int* __restrict__ cnt, int* __restrict__ bsum) {
    int tid = threadIdx.x;
    int i = blockIdx.x * 256 + tid;
    int lane = tid & 63, wid = tid >> 6;
    int v = (i < N_NODES) ? cnt[i] : 0;
#pragma unroll
    for (int off = 32; off; off >>= 1) v += __shfl_xor(v, off);
    __shared__ int wsum[4];
    if (lane == 0) wsum[wid] = v;
    __syncthreads();
    if (tid == 0) bsum[blockIdx.x] = wsum[0] + wsum[1] + wsum[2] + wsum[3];
}

__global__ void scanb_kernel(const int* __restrict__ bsum, int* __restrict__ boff,
                             int* __restrict__ rowptr) {
    int tid = threadIdx.x;          // 256
    int lane = tid & 63, wid = tid >> 6;
    int v = (tid < NB_SCAN) ? bsum[tid] : 0;
    int incl = v;
#pragma unroll
    for (int off = 1; off < 64; off <<= 1) {
        int t = __shfl_up(incl, off);
        if (lane >= off) incl += t;
    }
    __shared__ int wt[4];
    if (lane == 63) wt[wid] = incl;
    __syncthreads();
    int add = 0;
    for (int w = 0; w < wid; w++) add += wt[w];
    incl += add;
    if (tid < NB_SCAN) boff[tid] = incl - v;
    if (tid == NB_SCAN - 1) rowptr[N_NODES] = incl;
}

__global__ void scanc_kernel(const int* __restrict__ cnt, const int* __restrict__ boff,
                             int* __restrict__ rowptr) {
    int tid = threadIdx.x;
    int i = blockIdx.x * 256 + tid;
    int lane = tid & 63, wid = tid >> 6;
    int v = (i < N_NODES) ? cnt[i] : 0;
    int incl = v;
#pragma unroll
    for (int off = 1; off < 64; off <<= 1) {
        int t = __shfl_up(incl, off);
        if (lane >= off) incl += t;
    }
    __shared__ int wt[4];
    if (lane == 63) wt[wid] = incl;
    __syncthreads();
    int add = boff[blockIdx.x];
    for (int w = 0; w < wid; w++) add += wt[w];
    int excl = add + incl - v;
    if (i < N_NODES) rowptr[i] = excl;
}

// scatter with NO atomics: pos = rowptr[d] + erank[i]
__global__ void scatter_kernel(const int* __restrict__ ei, const int* __restrict__ rowptr,
                               const int* __restrict__ erank, int* __restrict__ csr_src) {
    int i = blockIdx.x * blockDim.x + threadIdx.x;
    if (i >= EP) return;
    int s, d;
    if (i < N_EDGES) { s = ei[i]; d = ei[N_EDGES + i]; }
    else             { s = d = i - N_EDGES; }
    csr_src[rowptr[d] + erank[i]] = s;
}

__device__ __forceinline__ float lrelu(float e) { return e > 0.f ? e : NEG_SLOPE * e; }

// ---------- layer-1 aggregate + FUSED layer-2 GEMM + alphas2 ----------
// 8 waves/block, 1 node/wave. W2 (128x64 fp32, 32KB) staged in LDS per block.
// After computing the act1 row (bias+relu, fp32, 2 ch/lane), stash it in a
// wave-private LDS row buffer and immediately compute h2 = row @ W2 + alphas2.
// act1 never touches global memory.
__global__ void __launch_bounds__(512)
node_agg1_fused(const int* __restrict__ rowptr, const int* __restrict__ csr_src,
                const uint* __restrict__ Hb,
                const float* __restrict__ as, const float* __restrict__ ad,
                const float* __restrict__ b,
                const float* __restrict__ W2,
                const float* __restrict__ as2w, const float* __restrict__ ad2w,
                ushort* __restrict__ Y2, float* __restrict__ as2, float* __restrict__ ad2) {
    __shared__ float w2s[128 * 64];     // 32 KB
    __shared__ float rowbuf[8][128];    // 4 KB, wave-private rows
    const int tid = threadIdx.x;
    const float4* W24 = (const float4*)W2;
    for (int idx = tid; idx < 128 * 16; idx += 512)
        ((float4*)w2s)[idx] = W24[idx];
    __syncthreads();   // only barrier; all later work is wave-local

    const int wave = tid >> 6;
    const int lane = tid & 63;
    const int node = blockIdx.x * 8 + wave;
    if (node >= N_NODES) return;
    const int lo = rowptr[node], hi = rowptr[node + 1];
    const float ad0 = ad[(size_t)node * 2 + 0], ad1 = ad[(size_t)node * 2 + 1];

    float exa0 = 0.f, exa1 = 0.f, exb0 = 0.f, exb1 = 0.f;
    int j1 = lo + lane;
    if (j1 < hi) {
        int s = csr_src[j1];
        float2 a = *(const float2*)&as[(size_t)s * 2];
        exa0 = __expf(lrelu(a.x + ad0));
        exa1 = __expf(lrelu(a.y + ad1));
    }
    int j2 = lo + 64 + lane;
    if (j2 < hi) {
        int s = csr_src[j2];
        float2 a = *(const float2*)&as[(size_t)s * 2];
        exb0 = __expf(lrelu(a.x + ad0));
        exb1 = __expf(lrelu(a.y + ad1));
    }
    float d0 = exa0 + exb0, d1 = exa1 + exb1;
    for (int j = lo + 128 + lane; j < hi; j += 64) {   // degree > 128 (rare)
        int s = csr_src[j];
        float2 a = *(const float2*)&as[(size_t)s * 2];
        d0 += __expf(lrelu(a.x + ad0));
        d1 += __expf(lrelu(a.y + ad1));
    }
#pragma unroll
    for (int off = 32; off; off >>= 1) {
        d0 += __shfl_xor(d0, off);
        d1 += __shfl_xor(d1, off);
    }
    const float inv = (lane < 32) ? (1.f / d0) : (1.f / d1);
    const bool h0side = (lane < 32);

    float acc0 = 0.f, acc1 = 0.f;
    const int deg = hi - lo;
    const int n1 = deg < 64 ? deg : 64;
    int j = 0;
    for (; j + 8 <= n1; j += 8) {
        int s0 = csr_src[lo + j + 0], s1 = csr_src[lo + j + 1];
        int s2 = csr_src[lo + j + 2], s3 = csr_src[lo + j + 3];
        int s4 = csr_src[lo + j + 4], s5 = csr_src[lo + j + 5];
        int s6 = csr_src[lo + j + 6], s7 = csr_src[lo + j + 7];
        uint u0 = Hb[(size_t)s0 * 64 + lane];
        uint u1 = Hb[(size_t)s1 * 64 + lane];
        uint u2 = Hb[(size_t)s2 * 64 + lane];
        uint u3 = Hb[(size_t)s3 * 64 + lane];
        uint u4 = Hb[(size_t)s4 * 64 + lane];
        uint u5 = Hb[(size_t)s5 * 64 + lane];
        uint u6 = Hb[(size_t)s6 * 64 + lane];
        uint u7 = Hb[(size_t)s7 * 64 + lane];
        float ca0 = __shfl(exa0, j + 0), cb0 = __shfl(exa1, j + 0);
        float ca1 = __shfl(exa0, j + 1), cb1 = __shfl(exa1, j + 1);
        float ca2 = __shfl(exa0, j + 2), cb2 = __shfl(exa1, j + 2);
        float ca3 = __shfl(exa0, j + 3), cb3 = __shfl(exa1, j + 3);
        float ca4 = __shfl(exa0, j + 4), cb4 = __shfl(exa1, j + 4);
        float ca5 = __shfl(exa0, j + 5), cb5 = __shfl(exa1, j + 5);
        float ca6 = __shfl(exa0, j + 6), cb6 = __shfl(exa1, j + 6);
        float ca7 = __shfl(exa0, j + 7), cb7 = __shfl(exa1, j + 7);
        float c0 = h0side ? ca0 : cb0;
        float c1 = h0side ? ca1 : cb1;
        float c2 = h0side ? ca2 : cb2;
        float c3 = h0side ? ca3 : cb3;
        float c4 = h0side ? ca4 : cb4;
        float c5 = h0side ? ca5 : cb5;
        float c6 = h0side ? ca6 : cb6;
        float c7 = h0side ? ca7 : cb7;
        acc0 = fmaf(bf_lo(u0), c0, acc0); acc1 = fmaf(bf_hi(u0), c0, acc1);
        acc0 = fmaf(bf_lo(u1), c1, acc0); acc1 = fmaf(bf_hi(u1), c1, acc1);
        acc0 = fmaf(bf_lo(u2), c2, acc0); acc1 = fmaf(bf_hi(u2), c2, acc1);
        acc0 = fmaf(bf_lo(u3), c3, acc0); acc1 = fmaf(bf_hi(u3), c3, acc1);
        acc0 = fmaf(bf_lo(u4), c4, acc0); acc1 = fmaf(bf_hi(u4), c4, acc1);
        acc0 = fmaf(bf_lo(u5), c5, acc0); acc1 = fmaf(bf_hi(u5), c5, acc1);
        acc0 = fmaf(bf_lo(u6), c6, acc0); acc1 = fmaf(bf_hi(u6), c6, acc1);
        acc0 = fmaf(bf_lo(u7), c7, acc0); acc1 = fmaf(bf_hi(u7), c7, acc1);
    }
    for (; j < n1; j++) {
        int s = csr_src[lo + j];
        float ca = __shfl(exa0, j), cb = __shfl(exa1, j);
        float c = h0side ? ca : cb;
        uint u = Hb[(size_t)s * 64 + lane];
        acc0 = fmaf(bf_lo(u), c, acc0);
        acc1 = fmaf(bf_hi(u), c, acc1);
    }
    if (deg > 64) {
        const int n2 = deg < 128 ? deg : 128;
        for (j = 64; j < n2; j++) {
            int s = csr_src[lo + j];
            float ca = __shfl(exb0, j - 64), cb = __shfl(exb1, j - 64);
            float c = h0side ? ca : cb;
            uint u = Hb[(size_t)s * 64 + lane];
            acc0 = fmaf(bf_lo(u), c, acc0);
            acc1 = fmaf(bf_hi(u), c, acc1);
        }
        for (int jj = lo + 128; jj < hi; jj++) {       // rare; lane-local, no shfl
            int s = csr_src[jj];
            float2 a = *(const float2*)&as[(size_t)s * 2];
            float e0 = __expf(lrelu(a.x + ad0));
            float e1 = __expf(lrelu(a.y + ad1));
            float c = h0side ? e0 : e1;
            uint u = Hb[(size_t)s * 64 + lane];
            acc0 = fmaf(bf_lo(u), c, acc0);
            acc1 = fmaf(bf_hi(u), c, acc1);
        }
    }
    float v0 = acc0 * inv + b[2 * lane];
    float v1 = acc1 * inv + b[2 * lane + 1];
    v0 = v0 > 0.f ? v0 : 0.f;
    v1 = v1 > 0.f ? v1 : 0.f;

    // ---- fused layer-2 GEMM: h2 = act1_row @ W2, alphas2, bf16 write ----
    rowbuf[wave][2 * lane]     = v0;
    rowbuf[wave][2 * lane + 1] = v1;   // wave-private; compiler orders LDS RAW
    float h2c = 0.f;
#pragma unroll
    for (int k4 = 0; k4 < 32; k4++) {
        float4 rv = *(const float4*)&rowbuf[wave][k4 * 4];
        h2c = fmaf(rv.x, w2s[(k4 * 4 + 0) * 64 + lane], h2c);
        h2c = fmaf(rv.y, w2s[(k4 * 4 + 1) * 64 + lane], h2c);
        h2c = fmaf(rv.z, w2s[(k4 * 4 + 2) * 64 + lane], h2c);
        h2c = fmaf(rv.w, w2s[(k4 * 4 + 3) * 64 + lane], h2c);
    }
    Y2[(size_t)node * 64 + lane] = f2bf(h2c);
    float s2 = h2c * as2w[lane];
    float d2 = h2c * ad2w[lane];
#pragma unroll
    for (int off = 32; off; off >>= 1) {
        s2 += __shfl_xor(s2, off);
        d2 += __shfl_xor(d2, off);
    }
    if (lane == 0) { as2[node] = s2; ad2[node] = d2; }
}

__global__ void node_agg2_kernel(const int* __restrict__ rowptr, const int* __restrict__ csr_src,
                                 const ushort* __restrict__ Hb,
                                 const float* __restrict__ as, const float* __restrict__ ad,
                                 const float* __restrict__ b, float* __restrict__ outp) {
    int wave = threadIdx.x >> 6;
    int lane = threadIdx.x & 63;
    int node = blockIdx.x * 4 + wave;
    if (node >= N_NODES) return;
    const int lo = rowptr[node], hi = rowptr[node + 1];
    const float adN = ad[node];

    float exa = 0.f, exb = 0.f;
    int j1 = lo + lane;
    if (j1 < hi) exa = __expf(lrelu(as[csr_src[j1]] + adN));
    int j2 = lo + 64 + lane;
    if (j2 < hi) exb = __expf(lrelu(as[csr_src[j2]] + adN));
    float d = exa + exb;
    for (int j = lo + 128 + lane; j < hi; j += 64)
        d += __expf(lrelu(as[csr_src[j]] + adN));
#pragma unroll
    for (int off = 32; off; off >>= 1) d += __shfl_xor(d, off);
    const float inv = 1.f / d;

    float acc = 0.f;
    const int deg = hi - lo;
    const int n1 = deg < 64 ? deg : 64;
    int j = 0;
    for (; j + 8 <= n1; j += 8) {
        int s0 = csr_src[lo + j + 0], s1 = csr_src[lo + j + 1];
        int s2 = csr_src[lo + j + 2], s3 = csr_src[lo + j + 3];
        int s4 = csr_src[lo + j + 4], s5 = csr_src[lo + j + 5];
        int s6 = csr_src[lo + j + 6], s7 = csr_src[lo + j + 7];
        float h0 = __uint_as_float(((uint)Hb[(size_t)s0 * 64 + lane]) << 16);
        float h1 = __uint_as_float(((uint)Hb[(size_t)s1 * 64 + lane]) << 16);
        float h2 = __uint_as_float(((uint)Hb[(size_t)s2 * 64 + lane]) << 16);
        float h3 = __uint_as_float(((uint)Hb[(size_t)s3 * 64 + lane]) << 16);
        float h4 = __uint_as_float(((uint)Hb[(size_t)s4 * 64 + lane]) << 16);
        float h5 = __uint_as_float(((uint)Hb[(size_t)s5 * 64 + lane]) << 16);
        float h6 = __uint_as_float(((uint)Hb[(size_t)s6 * 64 + lane]) << 16);
        float h7 = __uint_as_float(((uint)Hb[(size_t)s7 * 64 + lane]) << 16);
        float c0 = __shfl(exa, j + 0), c1 = __shfl(exa, j + 1);
        float c2 = __shfl(exa, j + 2), c3 = __shfl(exa, j + 3);
        float c4 = __shfl(exa, j + 4), c5 = __shfl(exa, j + 5);
        float c6 = __shfl(exa, j + 6), c7 = __shfl(exa, j + 7);
        acc = fmaf(h0, c0, acc);
        acc = fmaf(h1, c1, acc);
        acc = fmaf(h2, c2, acc);
        acc = fmaf(h3, c3, acc);
        acc = fmaf(h4, c4, acc);
        acc = fmaf(h5, c5, acc);
        acc = fmaf(h6, c6, acc);
        acc = fmaf(h7, c7, acc);
    }
    for (; j < n1; j++) {
        float c = __shfl(exa, j);
        acc = fmaf(__uint_as_float(((uint)Hb[(size_t)csr_src[lo + j] * 64 + lane]) << 16), c, acc);
    }
    if (deg > 64) {
        const int n2 = deg < 128 ? deg : 128;
        for (j = 64; j < n2; j++) {
            float c = __shfl(exb, j - 64);
            acc = fmaf(__uint_as_float(((uint)Hb[(size_t)csr_src[lo + j] * 64 + lane]) << 16), c, acc);
        }
        for (int jj = lo + 128; jj < hi; jj++) {       // rare
            int s = csr_src[jj];
            float c = __expf(lrelu(as[s] + adN));
            acc = fmaf(__uint_as_float(((uint)Hb[(size_t)s * 64 + lane]) << 16), c, acc);
        }
    }
    float v = acc * inv + b[lane];
    outp[(size_t)node * 64 + lane] = v > 0.f ? v : 0.f;
}

// ---------- pool + fc + log_softmax: 4 waves per graph ----------
__global__ void pool_fc_kernel(const float* __restrict__ act2,
                               const int* __restrict__ batch,
                               const float* __restrict__ fcW,
                               const float* __restrict__ fcb,
                               float* __restrict__ out) {
    int g = blockIdx.x;
    int tid = threadIdx.x;            // 256
    int wid = tid >> 6, c = tid & 63;
    __shared__ int slo, shi;
    if (tid == 0) {
        int lo = 0, hi = N_NODES;
        while (lo < hi) { int m = (lo + hi) >> 1; if (batch[m] < g) lo = m + 1; else hi = m; }
        slo = lo;
        lo = 0; hi = N_NODES;
        while (lo < hi) { int m = (lo + hi) >> 1; if (batch[m] < g + 1) lo = m + 1; else hi = m; }
        shi = lo;
    }
    __syncthreads();
    const int lo = slo, hi = shi;
    float sum = 0.f;
    for (int n = lo + wid; n < hi; n += 4) sum += act2[(size_t)n * HID + c];
    __shared__ float ps[4][HID];
    ps[wid][c] = sum;
    __syncthreads();
    if (wid == 0) {
        float t = ps[0][c] + ps[1][c] + ps[2][c] + ps[3][c];
        float cnt = (float)(hi - lo);
        __shared__ float pooled[HID];
        pooled[c] = t / fmaxf(cnt, 1.f);
        __syncthreads();
        __shared__ float ls[OUT_DIM];
        if (c < OUT_DIM) {
            float l = fcb[c];
#pragma unroll 8
            for (int k = 0; k < HID; k++) l = fmaf(pooled[k], fcW[k * OUT_DIM + c], l);
            ls[c] = l;
        }
        __syncthreads();
        if (c < OUT_DIM) {
            float m = fmaxf(ls[0], ls[1]);
            float lse = m + logf(expf(ls[0] - m) + expf(ls[1] - m));
            out[(size_t)g * OUT_DIM + c] = ls[c] - lse;
        }
    }
}

extern "C" void kernel_launch(void* const* d_in, const int* in_sizes, int n_in,
                              void* d_out, int out_size, void* d_ws, size_t ws_size,
                              hipStream_t stream) {
    const float* x    = (const float*)d_in[0];
    const int*   ei   = (const int*)d_in[1];
    const int*   batch= (const int*)d_in[2];
    const float* W1   = (const float*)d_in[3];
    const float* as1w = (const float*)d_in[4];
    const float* ad1w = (const float*)d_in[5];
    const float* b1   = (const float*)d_in[6];
    const float* W2   = (const float*)d_in[7];
    const float* as2w = (const float*)d_in[8];
    const float* ad2w = (const float*)d_in[9];
    const float* b2   = (const float*)d_in[10];
    const float* fcW  = (const float*)d_in[11];
    const float* fcb  = (const float*)d_in[12];

    const size_t N = N_NODES;
    float* ws = (float*)d_ws;
    ushort* h1b  = (ushort*)ws;               // N*128 bf16 = N*64 floats
    ushort* h2b  = (ushort*)(ws + N * 64);    // N*64 bf16 = N*32 floats
    float* out2  = ws + N * 64 + N * 32;      // N*64 fp32
    float* alps1 = out2 + N * 64;             // N*2
    float* alpd1 = alps1 + N * 2;             // N*2
    float* alps2 = alpd1 + N * 2;             // N
    float* alpd2 = alps2 + N;                 // N
    int* cnt     = (int*)(alpd2 + N);         // N
    int* rowptr  = cnt + N;                   // N+1
    int* bsum    = rowptr + N + 1;            // NB_SCAN
    int* boff    = bsum + NB_SCAN;            // NB_SCAN
    int* erank   = boff + NB_SCAN;            // EP
    int* csr_src = erank + EP;                // EP

    // ---- fused: layer-1 GEMM+alphas || edge histogram ----
    hipMemsetAsync(cnt, 0, N * sizeof(int), stream);
    fused_gemm1_hist<<<G_GEMM1 + G_HIST, 256, 0, stream>>>(
        x, W1, h1b, as1w, ad1w, alps1, alpd1, ei, cnt, erank);

    // ---- CSR finish ----
    partial_kernel<<<NB_SCAN, 256, 0, stream>>>(cnt, bsum);
    scanb_kernel<<<1, 256, 0, stream>>>(bsum, boff, rowptr);
    scanc_kernel<<<NB_SCAN, 256, 0, stream>>>(cnt, boff, rowptr);
    scatter_kernel<<<(EP + 255) / 256, 256, 0, stream>>>(ei, rowptr, erank, csr_src);

    // ---- layer-1 aggregate + fused layer-2 GEMM/alphas ----
    node_agg1_fused<<<(N + 7) / 8, 512, 0, stream>>>(
        rowptr, csr_src, (const uint*)h1b, alps1, alpd1, b1,
        W2, as2w, ad2w, h2b, alps2, alpd2);

    // ---- layer-2 aggregate ----
    node_agg2_kernel<<<(N + 3) / 4, 256, 0, stream>>>(
        rowptr, csr_src, h2b, alps2, alpd2, b2, out2);

    // ---- pool + fc + log_softmax ----
    pool_fc_kernel<<<N_GRAPHS, 256, 0, stream>>>(out2, batch, fcW, fcb, (float*)d_out);
}

// Round 13
// 307.101 us; speedup vs baseline: 1.0061x; 1.0061x over previous
//
#include <hip/hip_runtime.h>
#include <math.h>

#define N_NODES 50000
#define N_EDGES 800000
#define EP (N_EDGES + N_NODES)   // edges + self loops
#define IN_DIM 128
#define HID 64
#define HEADS 2
#define OUT_DIM 2
#define N_GRAPHS 512
#define NEG_SLOPE 0.2f
#define NB_SCAN 196              // ceil(50000/256)
#define GA_GEMM 782              // gemm blocks in kernel A (nodes [0, 25024))
#define GB_GEMM 781              // gemm blocks in kernel B (nodes [25024, 50000))
#define GB_BASE 25024
#define G_HIST 3321              // ceil(850000/256)
#define G_SCAT 3321

typedef unsigned int uint;
typedef unsigned short ushort;

// round-to-nearest-even f32 -> bf16
__device__ __forceinline__ ushort f2bf(float f) {
    uint u = __float_as_uint(f);
    u += 0x7fffu + ((u >> 16) & 1u);
    return (ushort)(u >> 16);
}
__device__ __forceinline__ float bf_lo(uint u) { return __uint_as_float(u << 16); }
__device__ __forceinline__ float bf_hi(uint u) { return __uint_as_float(u & 0xffff0000u); }
__device__ __forceinline__ float lrelu(float e) { return e > 0.f ? e : NEG_SLOPE * e; }

// ---------- layer-1 GEMM + alphas, one block of 4 waves x 8 nodes ----------
// Block-uniform call (blockIdx-based branch), so the __syncthreads is legal.
__device__ __forceinline__ void gemm1_block(float (*xs)[128], int base_block,
                                            const float* __restrict__ X,
                                            const float* __restrict__ W,
                                            ushort* __restrict__ Y,
                                            const float* __restrict__ a_src,
                                            const float* __restrict__ a_dst,
                                            float* __restrict__ as, float* __restrict__ ad) {
    const int wave = threadIdx.x >> 6;
    const int lane = threadIdx.x & 63;
    const int base = base_block + wave * 8;
    const float4* X4 = (const float4*)X;
    for (int idx = lane; idx < 8 * 32; idx += 64) {
        int r = idx >> 5, c = idx & 31;
        int n = base + r;
        float4 v = (n < N_NODES) ? X4[(size_t)n * 32 + c] : make_float4(0.f, 0.f, 0.f, 0.f);
        ((float4*)xs[wave * 8 + r])[c] = v;
    }
    __syncthreads();

    float acc0[8], acc1[8];
#pragma unroll
    for (int i = 0; i < 8; i++) { acc0[i] = 0.f; acc1[i] = 0.f; }
    for (int k = 0; k < 128; k += 4) {
        float wA[4], wB[4];
#pragma unroll
        for (int kk = 0; kk < 4; kk++) {
            wA[kk] = W[(size_t)(k + kk) * 128 + lane];
            wB[kk] = W[(size_t)(k + kk) * 128 + 64 + lane];
        }
#pragma unroll
        for (int i = 0; i < 8; i++) {
            float4 xv = *(const float4*)&xs[wave * 8 + i][k];
            acc0[i] = fmaf(xv.x, wA[0], acc0[i]); acc1[i] = fmaf(xv.x, wB[0], acc1[i]);
            acc0[i] = fmaf(xv.y, wA[1], acc0[i]); acc1[i] = fmaf(xv.y, wB[1], acc1[i]);
            acc0[i] = fmaf(xv.z, wA[2], acc0[i]); acc1[i] = fmaf(xv.z, wB[2], acc1[i]);
            acc0[i] = fmaf(xv.w, wA[3], acc0[i]); acc1[i] = fmaf(xv.w, wB[3], acc1[i]);
        }
    }

    const float asv0 = a_src[lane],      adv0 = a_dst[lane];
    const float asv1 = a_src[64 + lane], adv1 = a_dst[64 + lane];
#pragma unroll
    for (int i = 0; i < 8; i++) {
        int n = base + i;
        if (n >= N_NODES) continue;
        Y[(size_t)n * 128 + lane]      = f2bf(acc0[i]);
        Y[(size_t)n * 128 + 64 + lane] = f2bf(acc1[i]);
        float s0 = acc0[i] * asv0, d0 = acc0[i] * adv0;
        float s1 = acc1[i] * asv1, d1 = acc1[i] * adv1;
#pragma unroll
        for (int off = 32; off; off >>= 1) {
            s0 += __shfl_xor(s0, off);
            d0 += __shfl_xor(d0, off);
            s1 += __shfl_xor(s1, off);
            d1 += __shfl_xor(d1, off);
        }
        if (lane == 0) {
            as[(size_t)n * 2 + 0] = s0; as[(size_t)n * 2 + 1] = s1;
            ad[(size_t)n * 2 + 0] = d0; ad[(size_t)n * 2 + 1] = d1;
        }
    }
}

// ---------- kernel A: gemm1 first half || histogram ----------
__global__ void fused_gemm1a_hist(const float* __restrict__ X, const float* __restrict__ W,
                                  ushort* __restrict__ Y,
                                  const float* __restrict__ a_src, const float* __restrict__ a_dst,
                                  float* __restrict__ as, float* __restrict__ ad,
                                  const int* __restrict__ ei, int* __restrict__ cnt,
                                  int* __restrict__ erank) {
    __shared__ float xs[32][128];
    if (blockIdx.x >= GA_GEMM) {
        int i = (blockIdx.x - GA_GEMM) * 256 + threadIdx.x;
        if (i < EP) {
            int d = (i < N_EDGES) ? ei[N_EDGES + i] : (i - N_EDGES);
            erank[i] = atomicAdd(&cnt[d], 1);
        }
        return;
    }
    gemm1_block(xs, blockIdx.x * 32, X, W, Y, a_src, a_dst, as, ad);
}

// ---------- kernel B: gemm1 second half || scatter (no atomics) ----------
__global__ void fused_gemm1b_scatter(const float* __restrict__ X, const float* __restrict__ W,
                                     ushort* __restrict__ Y,
                                     const float* __restrict__ a_src, const float* __restrict__ a_dst,
                                     float* __restrict__ as, float* __restrict__ ad,
                                     const int* __restrict__ ei, const int* __restrict__ rowptr,
                                     const int* __restrict__ erank, int* __restrict__ csr_src) {
    __shared__ float xs[32][128];
    if (blockIdx.x >= GB_GEMM) {
        int i = (blockIdx.x - GB_GEMM) * 256 + threadIdx.x;
        if (i < EP) {
            int s, d;
            if (i < N_EDGES) { s = ei[i]; d = ei[N_EDGES + i]; }
            else             { s = d = i - N_EDGES; }
            csr_src[rowptr[d] + erank[i]] = s;
        }
        return;
    }
    gemm1_block(xs, GB_BASE + blockIdx.x * 32, X, W, Y, a_src, a_dst, as, ad);
}

__global__ void partial_kernel(const int* __restrict__ cnt, int* __restrict__ bsum) {
    int tid = threadIdx.x;
    int i = blockIdx.x * 256 + tid;
    int lane = tid & 63, wid = tid >> 6;
    int v = (i < N_NODES) ? cnt[i] : 0;
#pragma unroll
    for (int off = 32; off; off >>= 1) v += __shfl_xor(v, off);
    __shared__ int wsum[4];
    if (lane == 0) wsum[wid] = v;
    __syncthreads();
    if (tid == 0) bsum[blockIdx.x] = wsum[0] + wsum[1] + wsum[2] + wsum[3];
}

// merged scanb+scanc: each block re-scans bsum for its own offset, then
// block-level exclusive scan of cnt -> rowptr. Block 0 writes rowptr[N].
__global__ void scanc_kernel(const int* __restrict__ cnt, const int* __restrict__ bsum,
                             int* __restrict__ rowptr) {
    int tid = threadIdx.x;
    int lane = tid & 63, wid = tid >> 6;
    __shared__ int wtA[4], wtB[4];
    __shared__ int s_boff;

    // --- pass A: scan the 196 block sums ---
    int bv = (tid < NB_SCAN) ? bsum[tid] : 0;
    int bincl = bv;
#pragma unroll
    for (int off = 1; off < 64; off <<= 1) {
        int t = __shfl_up(bincl, off);
        if (lane >= off) bincl += t;
    }
    if (lane == 63) wtA[wid] = bincl;
    __syncthreads();
    int addA = 0;
    for (int w = 0; w < wid; w++) addA += wtA[w];
    bincl += addA;
    if (tid == blockIdx.x) s_boff = bincl - bv;            // blockIdx.x < 196 < 256
    if (blockIdx.x == 0 && tid == NB_SCAN - 1) rowptr[N_NODES] = bincl;

    // --- pass B: scan this block's 256 counts ---
    int i = blockIdx.x * 256 + tid;
    int v = (i < N_NODES) ? cnt[i] : 0;
    int incl = v;
#pragma unroll
    for (int off = 1; off < 64; off <<= 1) {
        int t = __shfl_up(incl, off);
        if (lane >= off) incl += t;
    }
    if (lane == 63) wtB[wid] = incl;
    __syncthreads();                                       // covers s_boff + wtB
    int add = s_boff;
    for (int w = 0; w < wid; w++) add += wtB[w];
    if (i < N_NODES) rowptr[i] = add + incl - v;
}

// ---------- layer-2 GEMM + fused alphas ----------
__global__ void gemm_alphas2(const float* __restrict__ X, const float* __restrict__ W,
                             ushort* __restrict__ Y,
                             const float* __restrict__ a_src, const float* __restrict__ a_dst,
                             float* __restrict__ as, float* __restrict__ ad, int n_nodes) {
    __shared__ float xs[8][128];
    const int base = blockIdx.x * 8;
    const int t = threadIdx.x;                 // 0..63
    const int g = t >> 5, c = t & 31;
    const float4* X4 = (const float4*)X;
    for (int idx = t; idx < 8 * 32; idx += 64) {
        int r = idx >> 5, cc = idx & 31;
        int n = base + r;
        float4 v = (n < n_nodes) ? X4[(size_t)n * 32 + cc] : make_float4(0.f, 0.f, 0.f, 0.f);
        ((float4*)xs[r])[cc] = v;
    }
    __syncthreads();

    float acc0[4], acc1[4];
#pragma unroll
    for (int i = 0; i < 4; i++) { acc0[i] = 0.f; acc1[i] = 0.f; }
    for (int k = 0; k < 128; k += 4) {
        float wA[4], wB[4];
#pragma unroll
        for (int kk = 0; kk < 4; kk++) {
            wA[kk] = W[(size_t)(k + kk) * 64 + c];
            wB[kk] = W[(size_t)(k + kk) * 64 + 32 + c];
        }
#pragma unroll
        for (int i = 0; i < 4; i++) {
            float4 xv = *(const float4*)&xs[g * 4 + i][k];
            acc0[i] = fmaf(xv.x, wA[0], acc0[i]); acc1[i] = fmaf(xv.x, wB[0], acc1[i]);
            acc0[i] = fmaf(xv.y, wA[1], acc0[i]); acc1[i] = fmaf(xv.y, wB[1], acc1[i]);
            acc0[i] = fmaf(xv.z, wA[2], acc0[i]); acc1[i] = fmaf(xv.z, wB[2], acc1[i]);
            acc0[i] = fmaf(xv.w, wA[3], acc0[i]); acc1[i] = fmaf(xv.w, wB[3], acc1[i]);
        }
    }

    const float asvA = a_src[c], asvB = a_src[32 + c];
    const float advA = a_dst[c], advB = a_dst[32 + c];
#pragma unroll
    for (int i = 0; i < 4; i++) {
        int n = base + g * 4 + i;
        if (n >= n_nodes) continue;
        Y[(size_t)n * 64 + c]      = f2bf(acc0[i]);
        Y[(size_t)n * 64 + 32 + c] = f2bf(acc1[i]);
        float s = acc0[i] * asvA + acc1[i] * asvB;
        float d = acc0[i] * advA + acc1[i] * advB;
#pragma unroll
        for (int off = 16; off; off >>= 1) {
            s += __shfl_xor(s, off);
            d += __shfl_xor(d, off);
        }
        if (c == 0) { as[n] = s; ad[n] = d; }
    }
}

// ---------- fused per-node softmax + aggregate + bias + relu ----------
__global__ void node_agg1_kernel(const int* __restrict__ rowptr, const int* __restrict__ csr_src,
                                 const uint* __restrict__ Hb,
                                 const float* __restrict__ as, const float* __restrict__ ad,
                                 const float* __restrict__ b, float* __restrict__ outp) {
    int wave = threadIdx.x >> 6;
    int lane = threadIdx.x & 63;
    int node = blockIdx.x * 4 + wave;
    if (node >= N_NODES) return;
    const int lo = rowptr[node], hi = rowptr[node + 1];
    const float ad0 = ad[(size_t)node * 2 + 0], ad1 = ad[(size_t)node * 2 + 1];

    float exa0 = 0.f, exa1 = 0.f, exb0 = 0.f, exb1 = 0.f;
    int j1 = lo + lane;
    if (j1 < hi) {
        int s = csr_src[j1];
        float2 a = *(const float2*)&as[(size_t)s * 2];
        exa0 = __expf(lrelu(a.x + ad0));
        exa1 = __expf(lrelu(a.y + ad1));
    }
    int j2 = lo + 64 + lane;
    if (j2 < hi) {
        int s = csr_src[j2];
        float2 a = *(const float2*)&as[(size_t)s * 2];
        exb0 = __expf(lrelu(a.x + ad0));
        exb1 = __expf(lrelu(a.y + ad1));
    }
    float d0 = exa0 + exb0, d1 = exa1 + exb1;
    for (int j = lo + 128 + lane; j < hi; j += 64) {   // degree > 128 (rare)
        int s = csr_src[j];
        float2 a = *(const float2*)&as[(size_t)s * 2];
        d0 += __expf(lrelu(a.x + ad0));
        d1 += __expf(lrelu(a.y + ad1));
    }
#pragma unroll
    for (int off = 32; off; off >>= 1) {
        d0 += __shfl_xor(d0, off);
        d1 += __shfl_xor(d1, off);
    }
    const float inv = (lane < 32) ? (1.f / d0) : (1.f / d1);
    const bool h0side = (lane < 32);

    float acc0 = 0.f, acc1 = 0.f;
    const int deg = hi - lo;
    const int n1 = deg < 64 ? deg : 64;
    int j = 0;
    for (; j + 8 <= n1; j += 8) {
        int s0 = csr_src[lo + j + 0], s1 = csr_src[lo + j + 1];
        int s2 = csr_src[lo + j + 2], s3 = csr_src[lo + j + 3];
        int s4 = csr_src[lo + j + 4], s5 = csr_src[lo + j + 5];
        int s6 = csr_src[lo + j + 6], s7 = csr_src[lo + j + 7];
        uint u0 = Hb[(size_t)s0 * 64 + lane];
        uint u1 = Hb[(size_t)s1 * 64 + lane];
        uint u2 = Hb[(size_t)s2 * 64 + lane];
        uint u3 = Hb[(size_t)s3 * 64 + lane];
        uint u4 = Hb[(size_t)s4 * 64 + lane];
        uint u5 = Hb[(size_t)s5 * 64 + lane];
        uint u6 = Hb[(size_t)s6 * 64 + lane];
        uint u7 = Hb[(size_t)s7 * 64 + lane];
        float ca0 = __shfl(exa0, j + 0), cb0 = __shfl(exa1, j + 0);
        float ca1 = __shfl(exa0, j + 1), cb1 = __shfl(exa1, j + 1);
        float ca2 = __shfl(exa0, j + 2), cb2 = __shfl(exa1, j + 2);
        float ca3 = __shfl(exa0, j + 3), cb3 = __shfl(exa1, j + 3);
        float ca4 = __shfl(exa0, j + 4), cb4 = __shfl(exa1, j + 4);
        float ca5 = __shfl(exa0, j + 5), cb5 = __shfl(exa1, j + 5);
        float ca6 = __shfl(exa0, j + 6), cb6 = __shfl(exa1, j + 6);
        float ca7 = __shfl(exa0, j + 7), cb7 = __shfl(exa1, j + 7);
        float c0 = h0side ? ca0 : cb0;
        float c1 = h0side ? ca1 : cb1;
        float c2 = h0side ? ca2 : cb2;
        float c3 = h0side ? ca3 : cb3;
        float c4 = h0side ? ca4 : cb4;
        float c5 = h0side ? ca5 : cb5;
        float c6 = h0side ? ca6 : cb6;
        float c7 = h0side ? ca7 : cb7;
        acc0 = fmaf(bf_lo(u0), c0, acc0); acc1 = fmaf(bf_hi(u0), c0, acc1);
        acc0 = fmaf(bf_lo(u1), c1, acc0); acc1 = fmaf(bf_hi(u1), c1, acc1);
        acc0 = fmaf(bf_lo(u2), c2, acc0); acc1 = fmaf(bf_hi(u2), c2, acc1);
        acc0 = fmaf(bf_lo(u3), c3, acc0); acc1 = fmaf(bf_hi(u3), c3, acc1);
        acc0 = fmaf(bf_lo(u4), c4, acc0); acc1 = fmaf(bf_hi(u4), c4, acc1);
        acc0 = fmaf(bf_lo(u5), c5, acc0); acc1 = fmaf(bf_hi(u5), c5, acc1);
        acc0 = fmaf(bf_lo(u6), c6, acc0); acc1 = fmaf(bf_hi(u6), c6, acc1);
        acc0 = fmaf(bf_lo(u7), c7, acc0); acc1 = fmaf(bf_hi(u7), c7, acc1);
    }
    for (; j < n1; j++) {
        int s = csr_src[lo + j];
        float ca = __shfl(exa0, j), cb = __shfl(exa1, j);
        float c = h0side ? ca : cb;
        uint u = Hb[(size_t)s * 64 + lane];
        acc0 = fmaf(bf_lo(u), c, acc0);
        acc1 = fmaf(bf_hi(u), c, acc1);
    }
    if (deg > 64) {
        const int n2 = deg < 128 ? deg : 128;
        for (j = 64; j < n2; j++) {
            int s = csr_src[lo + j];
            float ca = __shfl(exb0, j - 64), cb = __shfl(exb1, j - 64);
            float c = h0side ? ca : cb;
            uint u = Hb[(size_t)s * 64 + lane];
            acc0 = fmaf(bf_lo(u), c, acc0);
            acc1 = fmaf(bf_hi(u), c, acc1);
        }
        for (int jj = lo + 128; jj < hi; jj++) {       // rare; lane-local, no shfl
            int s = csr_src[jj];
            float2 a = *(const float2*)&as[(size_t)s * 2];
            float e0 = __expf(lrelu(a.x + ad0));
            float e1 = __expf(lrelu(a.y + ad1));
            float c = h0side ? e0 : e1;
            uint u = Hb[(size_t)s * 64 + lane];
            acc0 = fmaf(bf_lo(u), c, acc0);
            acc1 = fmaf(bf_hi(u), c, acc1);
        }
    }
    float v0 = acc0 * inv + b[2 * lane];
    float v1 = acc1 * inv + b[2 * lane + 1];
    v0 = v0 > 0.f ? v0 : 0.f;
    v1 = v1 > 0.f ? v1 : 0.f;
    *(float2*)&outp[(size_t)node * 128 + 2 * lane] = make_float2(v0, v1);
}

__global__ void node_agg2_kernel(const int* __restrict__ rowptr, const int* __restrict__ csr_src,
                                 const ushort* __restrict__ Hb,
                                 const float* __restrict__ as, const float* __restrict__ ad,
                                 const float* __restrict__ b, float* __restrict__ outp) {
    int wave = threadIdx.x >> 6;
    int lane = threadIdx.x & 63;
    int node = blockIdx.x * 4 + wave;
    if (node >= N_NODES) return;
    const int lo = rowptr[node], hi = rowptr[node + 1];
    const float adN = ad[node];

    float exa = 0.f, exb = 0.f;
    int j1 = lo + lane;
    if (j1 < hi) exa = __expf(lrelu(as[csr_src[j1]] + adN));
    int j2 = lo + 64 + lane;
    if (j2 < hi) exb = __expf(lrelu(as[csr_src[j2]] + adN));
    float d = exa + exb;
    for (int j = lo + 128 + lane; j < hi; j += 64)
        d += __expf(lrelu(as[csr_src[j]] + adN));
#pragma unroll
    for (int off = 32; off; off >>= 1) d += __shfl_xor(d, off);
    const float inv = 1.f / d;

    float acc = 0.f;
    const int deg = hi - lo;
    const int n1 = deg < 64 ? deg : 64;
    int j = 0;
    for (; j + 8 <= n1; j += 8) {
        int s0 = csr_src[lo + j + 0], s1 = csr_src[lo + j + 1];
        int s2 = csr_src[lo + j + 2], s3 = csr_src[lo + j + 3];
        int s4 = csr_src[lo + j + 4], s5 = csr_src[lo + j + 5];
        int s6 = csr_src[lo + j + 6], s7 = csr_src[lo + j + 7];
        float h0 = __uint_as_float(((uint)Hb[(size_t)s0 * 64 + lane]) << 16);
        float h1 = __uint_as_float(((uint)Hb[(size_t)s1 * 64 + lane]) << 16);
        float h2 = __uint_as_float(((uint)Hb[(size_t)s2 * 64 + lane]) << 16);
        float h3 = __uint_as_float(((uint)Hb[(size_t)s3 * 64 + lane]) << 16);
        float h4 = __uint_as_float(((uint)Hb[(size_t)s4 * 64 + lane]) << 16);
        float h5 = __uint_as_float(((uint)Hb[(size_t)s5 * 64 + lane]) << 16);
        float h6 = __uint_as_float(((uint)Hb[(size_t)s6 * 64 + lane]) << 16);
        float h7 = __uint_as_float(((uint)Hb[(size_t)s7 * 64 + lane]) << 16);
        float c0 = __shfl(exa, j + 0), c1 = __shfl(exa, j + 1);
        float c2 = __shfl(exa, j + 2), c3 = __shfl(exa, j + 3);
        float c4 = __shfl(exa, j + 4), c5 = __shfl(exa, j + 5);
        float c6 = __shfl(exa, j + 6), c7 = __shfl(exa, j + 7);
        acc = fmaf(h0, c0, acc);
        acc = fmaf(h1, c1, acc);
        acc = fmaf(h2, c2, acc);
        acc = fmaf(h3, c3, acc);
        acc = fmaf(h4, c4, acc);
        acc = fmaf(h5, c5, acc);
        acc = fmaf(h6, c6, acc);
        acc = fmaf(h7, c7, acc);
    }
    for (; j < n1; j++) {
        float c = __shfl(exa, j);
        acc = fmaf(__uint_as_float(((uint)Hb[(size_t)csr_src[lo + j] * 64 + lane]) << 16), c, acc);
    }
    if (deg > 64) {
        const int n2 = deg < 128 ? deg : 128;
        for (j = 64; j < n2; j++) {
            float c = __shfl(exb, j - 64);
            acc = fmaf(__uint_as_float(((uint)Hb[(size_t)csr_src[lo + j] * 64 + lane]) << 16), c, acc);
        }
        for (int jj = lo + 128; jj < hi; jj++) {       // rare
            int s = csr_src[jj];
            float c = __expf(lrelu(as[s] + adN));
            acc = fmaf(__uint_as_float(((uint)Hb[(size_t)s * 64 + lane]) << 16), c, acc);
        }
    }
    float v = acc * inv + b[lane];
    outp[(size_t)node * 64 + lane] = v > 0.f ? v : 0.f;
}

// ---------- pool + fc + log_softmax: 4 waves per graph ----------
__global__ void pool_fc_kernel(const float* __restrict__ act2,
                               const int* __restrict__ batch,
                               const float* __restrict__ fcW,
                               const float* __restrict__ fcb,
                               float* __restrict__ out) {
    int g = blockIdx.x;
    int tid = threadIdx.x;            // 256
    int wid = tid >> 6, c = tid & 63;
    __shared__ int slo, shi;
    if (tid == 0) {
        int lo = 0, hi = N_NODES;
        while (lo < hi) { int m = (lo + hi) >> 1; if (batch[m] < g) lo = m + 1; else hi = m; }
        slo = lo;
        lo = 0; hi = N_NODES;
        while (lo < hi) { int m = (lo + hi) >> 1; if (batch[m] < g + 1) lo = m + 1; else hi = m; }
        shi = lo;
    }
    __syncthreads();
    const int lo = slo, hi = shi;
    float sum = 0.f;
    for (int n = lo + wid; n < hi; n += 4) sum += act2[(size_t)n * HID + c];
    __shared__ float ps[4][HID];
    ps[wid][c] = sum;
    __syncthreads();
    if (wid == 0) {
        float t = ps[0][c] + ps[1][c] + ps[2][c] + ps[3][c];
        float cnt = (float)(hi - lo);
        __shared__ float pooled[HID];
        pooled[c] = t / fmaxf(cnt, 1.f);
        __syncthreads();
        __shared__ float ls[OUT_DIM];
        if (c < OUT_DIM) {
            float l = fcb[c];
#pragma unroll 8
            for (int k = 0; k < HID; k++) l = fmaf(pooled[k], fcW[k * OUT_DIM + c], l);
            ls[c] = l;
        }
        __syncthreads();
        if (c < OUT_DIM) {
            float m = fmaxf(ls[0], ls[1]);
            float lse = m + logf(expf(ls[0] - m) + expf(ls[1] - m));
            out[(size_t)g * OUT_DIM + c] = ls[c] - lse;
        }
    }
}

extern "C" void kernel_launch(void* const* d_in, const int* in_sizes, int n_in,
                              void* d_out, int out_size, void* d_ws, size_t ws_size,
                              hipStream_t stream) {
    const float* x    = (const float*)d_in[0];
    const int*   ei   = (const int*)d_in[1];
    const int*   batch= (const int*)d_in[2];
    const float* W1   = (const float*)d_in[3];
    const float* as1w = (const float*)d_in[4];
    const float* ad1w = (const float*)d_in[5];
    const float* b1   = (const float*)d_in[6];
    const float* W2   = (const float*)d_in[7];
    const float* as2w = (const float*)d_in[8];
    const float* ad2w = (const float*)d_in[9];
    const float* b2   = (const float*)d_in[10];
    const float* fcW  = (const float*)d_in[11];
    const float* fcb  = (const float*)d_in[12];

    const size_t N = N_NODES;
    float* ws = (float*)d_ws;
    ushort* h1b  = (ushort*)ws;               // N*128 bf16 = N*64 floats
    float* act1  = ws + N * 64;               // N*128 fp32
    ushort* h2b  = (ushort*)(act1 + N * 128); // N*64 bf16 = N*32 floats
    float* out2  = act1 + N * 128 + N * 32;   // N*64 fp32
    float* alps1 = out2 + N * 64;             // N*2
    float* alpd1 = alps1 + N * 2;             // N*2
    float* alps2 = alpd1 + N * 2;             // N
    float* alpd2 = alps2 + N;                 // N
    int* cnt     = (int*)(alpd2 + N);         // N
    int* rowptr  = cnt + N;                   // N+1
    int* bsum    = rowptr + N + 1;            // NB_SCAN
    int* erank   = bsum + NB_SCAN;            // EP
    int* csr_src = erank + EP;                // EP

    // ---- kernel A: gemm1 (nodes [0,25024)) || histogram ----
    hipMemsetAsync(cnt, 0, N * sizeof(int), stream);
    fused_gemm1a_hist<<<GA_GEMM + G_HIST, 256, 0, stream>>>(
        x, W1, h1b, as1w, ad1w, alps1, alpd1, ei, cnt, erank);

    // ---- scan (2 kernels) ----
    partial_kernel<<<NB_SCAN, 256, 0, stream>>>(cnt, bsum);
    scanc_kernel<<<NB_SCAN, 256, 0, stream>>>(cnt, bsum, rowptr);

    // ---- kernel B: gemm1 (nodes [25024,50000)) || scatter ----
    fused_gemm1b_scatter<<<GB_GEMM + G_SCAT, 256, 0, stream>>>(
        x, W1, h1b, as1w, ad1w, alps1, alpd1, ei, rowptr, erank, csr_src);

    // ---- layer 1 aggregate ----
    node_agg1_kernel<<<(N + 3) / 4, 256, 0, stream>>>(
        rowptr, csr_src, (const uint*)h1b, alps1, alpd1, b1, act1);

    // ---- layer 2 ----
    gemm_alphas2<<<(N + 7) / 8, 64, 0, stream>>>(
        act1, W2, h2b, as2w, ad2w, alps2, alpd2, (int)N);
    node_agg2_kernel<<<(N + 3) / 4, 256, 0, stream>>>(
        rowptr, csr_src, h2b, alps2, alpd2, b2, out2);

    // ---- pool + fc + log_softmax ----
    pool_fc_kernel<<<N_GRAPHS, 256, 0, stream>>>(out2, batch, fcW, fcb, (float*)d_out);
}

// Round 16
// 303.623 us; speedup vs baseline: 1.0176x; 1.0115x over previous
//
#include <hip/hip_runtime.h>
#include <math.h>
#include <stdint.h>

#define N_NODES 50000
#define N_EDGES 800000
#define EP (N_EDGES + N_NODES)   // edges + self loops
#define IN_DIM 128
#define HID 64
#define HEADS 2
#define OUT_DIM 2
#define N_GRAPHS 512
#define NEG_SLOPE 0.2f
#define NB_SCAN 196              // ceil(50000/256)
#define G_GEMM1 1563             // ceil(50000/32) blocks of 4 waves x 8 nodes
#define G_HIST 3321              // ceil(850000/256)
#define NBKT 208                 // ceil(850000/4096)

typedef unsigned int uint;
typedef unsigned short ushort;

// round-to-nearest-even f32 -> bf16
__device__ __forceinline__ ushort f2bf(float f) {
    uint u = __float_as_uint(f);
    u += 0x7fffu + ((u >> 16) & 1u);
    return (ushort)(u >> 16);
}
__device__ __forceinline__ float bf_lo(uint u) { return __uint_as_float(u << 16); }
__device__ __forceinline__ float bf_hi(uint u) { return __uint_as_float(u & 0xffff0000u); }
__device__ __forceinline__ float lrelu(float e) { return e > 0.f ? e : NEG_SLOPE * e; }

// ---------- fused: layer-1 GEMM+alphas (blocks [0,G_GEMM1)) + histogram ----------
__global__ void fused_gemm1_hist(const float* __restrict__ X, const float* __restrict__ W,
                                 ushort* __restrict__ Y,
                                 const float* __restrict__ a_src, const float* __restrict__ a_dst,
                                 float* __restrict__ as, float* __restrict__ ad,
                                 const int* __restrict__ ei, int* __restrict__ cnt,
                                 int* __restrict__ erank) {
    if (blockIdx.x >= G_GEMM1) {
        int i = (blockIdx.x - G_GEMM1) * 256 + threadIdx.x;
        if (i < EP) {
            int d = (i < N_EDGES) ? ei[N_EDGES + i] : (i - N_EDGES);
            erank[i] = atomicAdd(&cnt[d], 1);
        }
        return;
    }
    __shared__ float xs[32][128];
    const int wave = threadIdx.x >> 6;
    const int lane = threadIdx.x & 63;
    const int base = blockIdx.x * 32 + wave * 8;
    const float4* X4 = (const float4*)X;
    for (int idx = lane; idx < 8 * 32; idx += 64) {
        int r = idx >> 5, c = idx & 31;
        int n = base + r;
        float4 v = (n < N_NODES) ? X4[(size_t)n * 32 + c] : make_float4(0.f, 0.f, 0.f, 0.f);
        ((float4*)xs[wave * 8 + r])[c] = v;
    }
    __syncthreads();

    float acc0[8], acc1[8];
#pragma unroll
    for (int i = 0; i < 8; i++) { acc0[i] = 0.f; acc1[i] = 0.f; }
    for (int k = 0; k < 128; k += 4) {
        float wA[4], wB[4];
#pragma unroll
        for (int kk = 0; kk < 4; kk++) {
            wA[kk] = W[(size_t)(k + kk) * 128 + lane];
            wB[kk] = W[(size_t)(k + kk) * 128 + 64 + lane];
        }
#pragma unroll
        for (int i = 0; i < 8; i++) {
            float4 xv = *(const float4*)&xs[wave * 8 + i][k];
            acc0[i] = fmaf(xv.x, wA[0], acc0[i]); acc1[i] = fmaf(xv.x, wB[0], acc1[i]);
            acc0[i] = fmaf(xv.y, wA[1], acc0[i]); acc1[i] = fmaf(xv.y, wB[1], acc1[i]);
            acc0[i] = fmaf(xv.z, wA[2], acc0[i]); acc1[i] = fmaf(xv.z, wB[2], acc1[i]);
            acc0[i] = fmaf(xv.w, wA[3], acc0[i]); acc1[i] = fmaf(xv.w, wB[3], acc1[i]);
        }
    }

    const float asv0 = a_src[lane],      adv0 = a_dst[lane];
    const float asv1 = a_src[64 + lane], adv1 = a_dst[64 + lane];
#pragma unroll
    for (int i = 0; i < 8; i++) {
        int n = base + i;
        if (n >= N_NODES) continue;
        Y[(size_t)n * 128 + lane]      = f2bf(acc0[i]);
        Y[(size_t)n * 128 + 64 + lane] = f2bf(acc1[i]);
        float s0 = acc0[i] * asv0, d0 = acc0[i] * adv0;
        float s1 = acc1[i] * asv1, d1 = acc1[i] * adv1;
#pragma unroll
        for (int off = 32; off; off >>= 1) {
            s0 += __shfl_xor(s0, off);
            d0 += __shfl_xor(d0, off);
            s1 += __shfl_xor(s1, off);
            d1 += __shfl_xor(d1, off);
        }
        if (lane == 0) {
            as[(size_t)n * 2 + 0] = s0; as[(size_t)n * 2 + 1] = s1;
            ad[(size_t)n * 2 + 0] = d0; ad[(size_t)n * 2 + 1] = d1;
        }
    }
}

__global__ void partial_kernel(const int* __restrict__ cnt, int* __restrict__ bsum,
                               int* __restrict__ gcursor) {
    int tid = threadIdx.x;
    if (blockIdx.x == 0 && tid < NBKT) gcursor[tid] = tid * 4096;
    int i = blockIdx.x * 256 + tid;
    int lane = tid & 63, wid = tid >> 6;
    int v = (i < N_NODES) ? cnt[i] : 0;
#pragma unroll
    for (int off = 32; off; off >>= 1) v += __shfl_xor(v, off);
    __shared__ int wsum[4];
    if (lane == 0) wsum[wid] = v;
    __syncthreads();
    if (tid == 0) bsum[blockIdx.x] = wsum[0] + wsum[1] + wsum[2] + wsum[3];
}

// merged scanb+scanc: each block re-scans bsum for its own offset, then
// block-level exclusive scan of cnt -> rowptr. Block 0 writes rowptr[N].
__global__ void scanc_kernel(const int* __restrict__ cnt, const int* __restrict__ bsum,
                             int* __restrict__ rowptr) {
    int tid = threadIdx.x;
    int lane = tid & 63, wid = tid >> 6;
    __shared__ int wtA[4], wtB[4];
    __shared__ int s_boff;

    int bv = (tid < NB_SCAN) ? bsum[tid] : 0;
    int bincl = bv;
#pragma unroll
    for (int off = 1; off < 64; off <<= 1) {
        int t = __shfl_up(bincl, off);
        if (lane >= off) bincl += t;
    }
    if (lane == 63) wtA[wid] = bincl;
    __syncthreads();
    int addA = 0;
    for (int w = 0; w < wid; w++) addA += wtA[w];
    bincl += addA;
    if (tid == blockIdx.x) s_boff = bincl - bv;
    if (blockIdx.x == 0 && tid == NB_SCAN - 1) rowptr[N_NODES] = bincl;

    int i = blockIdx.x * 256 + tid;
    int v = (i < N_NODES) ? cnt[i] : 0;
    int incl = v;
#pragma unroll
    for (int off = 1; off < 64; off <<= 1) {
        int t = __shfl_up(incl, off);
        if (lane >= off) incl += t;
    }
    if (lane == 63) wtB[wid] = incl;
    __syncthreads();
    int add = s_boff;
    for (int w = 0; w < wid; w++) add += wtB[w];
    if (i < N_NODES) rowptr[i] = add + incl - v;
}

// ---------- bucketed scatter (no line thrash) ----------
// pos = rowptr[d] + erank[i] is a bijection onto [0, EP). Bucket by pos>>12
// (4096-entry regions). Pass A groups (pos,s) pairs per bucket; pass B builds
// each 16KB csr region in LDS and dumps it sequentially.
__global__ void bucketA_kernel(const int* __restrict__ ei, const int* __restrict__ rowptr,
                               const int* __restrict__ erank, int* __restrict__ gcursor,
                               int2* __restrict__ pairbuf) {
    __shared__ int bcnt[NBKT];
    __shared__ int bbase[NBKT];
    const int tid = threadIdx.x;
    for (int b = tid; b < NBKT; b += 256) bcnt[b] = 0;
    __syncthreads();
    int pos[16], sv[16];
    const int base_i = blockIdx.x * 4096;
#pragma unroll
    for (int k = 0; k < 16; k++) {
        int i = base_i + k * 256 + tid;
        pos[k] = -1;
        if (i < EP) {
            int s, d;
            if (i < N_EDGES) { s = ei[i]; d = ei[N_EDGES + i]; }
            else             { s = d = i - N_EDGES; }
            int p = rowptr[d] + erank[i];
            pos[k] = p; sv[k] = s;
            atomicAdd(&bcnt[p >> 12], 1);
        }
    }
    __syncthreads();
    for (int b = tid; b < NBKT; b += 256) {
        int c = bcnt[b];
        bbase[b] = (c > 0) ? atomicAdd(&gcursor[b], c) : 0;
    }
    __syncthreads();
    for (int b = tid; b < NBKT; b += 256) bcnt[b] = 0;
    __syncthreads();
#pragma unroll
    for (int k = 0; k < 16; k++) {
        if (pos[k] >= 0) {
            int b = pos[k] >> 12;
            int r = atomicAdd(&bcnt[b], 1);
            pairbuf[bbase[b] + r] = make_int2(pos[k], sv[k]);
        }
    }
}

__global__ void bucketB_kernel(const int2* __restrict__ pairbuf, int* __restrict__ csr_src) {
    __shared__ int sbuf[4096];
    const int tid = threadIdx.x;
    const int base = blockIdx.x * 4096;
    const int cnt = (EP - base < 4096) ? (EP - base) : 4096;
    for (int j = tid; j < cnt; j += 256) {
        int2 pr = pairbuf[base + j];
        sbuf[pr.x - base] = pr.y;
    }
    __syncthreads();
    for (int j = tid; j < cnt; j += 256)
        csr_src[base + j] = sbuf[j];
}

// ---------- layer-2 GEMM + fused alphas ----------
__global__ void gemm_alphas2(const float* __restrict__ X, const float* __restrict__ W,
                             ushort* __restrict__ Y,
                             const float* __restrict__ a_src, const float* __restrict__ a_dst,
                             float* __restrict__ as, float* __restrict__ ad, int n_nodes) {
    __shared__ float xs[8][128];
    const int base = blockIdx.x * 8;
    const int t = threadIdx.x;                 // 0..63
    const int g = t >> 5, c = t & 31;
    const float4* X4 = (const float4*)X;
    for (int idx = t; idx < 8 * 32; idx += 64) {
        int r = idx >> 5, cc = idx & 31;
        int n = base + r;
        float4 v = (n < n_nodes) ? X4[(size_t)n * 32 + cc] : make_float4(0.f, 0.f, 0.f, 0.f);
        ((float4*)xs[r])[cc] = v;
    }
    __syncthreads();

    float acc0[4], acc1[4];
#pragma unroll
    for (int i = 0; i < 4; i++) { acc0[i] = 0.f; acc1[i] = 0.f; }
    for (int k = 0; k < 128; k += 4) {
        float wA[4], wB[4];
#pragma unroll
        for (int kk = 0; kk < 4; kk++) {
            wA[kk] = W[(size_t)(k + kk) * 64 + c];
            wB[kk] = W[(size_t)(k + kk) * 64 + 32 + c];
        }
#pragma unroll
        for (int i = 0; i < 4; i++) {
            float4 xv = *(const float4*)&xs[g * 4 + i][k];
            acc0[i] = fmaf(xv.x, wA[0], acc0[i]); acc1[i] = fmaf(xv.x, wB[0], acc1[i]);
            acc0[i] = fmaf(xv.y, wA[1], acc0[i]); acc1[i] = fmaf(xv.y, wB[1], acc1[i]);
            acc0[i] = fmaf(xv.z, wA[2], acc0[i]); acc1[i] = fmaf(xv.z, wB[2], acc1[i]);
            acc0[i] = fmaf(xv.w, wA[3], acc0[i]); acc1[i] = fmaf(xv.w, wB[3], acc1[i]);
        }
    }

    const float asvA = a_src[c], asvB = a_src[32 + c];
    const float advA = a_dst[c], advB = a_dst[32 + c];
#pragma unroll
    for (int i = 0; i < 4; i++) {
        int n = base + g * 4 + i;
        if (n >= n_nodes) continue;
        Y[(size_t)n * 64 + c]      = f2bf(acc0[i]);
        Y[(size_t)n * 64 + 32 + c] = f2bf(acc1[i]);
        float s = acc0[i] * asvA + acc1[i] * asvB;
        float d = acc0[i] * advA + acc1[i] * advB;
#pragma unroll
        for (int off = 16; off; off >>= 1) {
            s += __shfl_xor(s, off);
            d += __shfl_xor(d, off);
        }
        if (c == 0) { as[n] = s; ad[n] = d; }
    }
}

// ---------- fused per-node softmax + aggregate + bias + relu ----------
__global__ void node_agg1_kernel(const int* __restrict__ rowptr, const int* __restrict__ csr_src,
                                 const uint* __restrict__ Hb,
                                 const float* __restrict__ as, const float* __restrict__ ad,
                                 const float* __restrict__ b, float* __restrict__ outp) {
    int wave = threadIdx.x >> 6;
    int lane = threadIdx.x & 63;
    int node = blockIdx.x * 4 + wave;
    if (node >= N_NODES) return;
    const int lo = rowptr[node], hi = rowptr[node + 1];
    const float ad0 = ad[(size_t)node * 2 + 0], ad1 = ad[(size_t)node * 2 + 1];

    float exa0 = 0.f, exa1 = 0.f, exb0 = 0.f, exb1 = 0.f;
    int j1 = lo + lane;
    if (j1 < hi) {
        int s = csr_src[j1];
        float2 a = *(const float2*)&as[(size_t)s * 2];
        exa0 = __expf(lrelu(a.x + ad0));
        exa1 = __expf(lrelu(a.y + ad1));
    }
    int j2 = lo + 64 + lane;
    if (j2 < hi) {
        int s = csr_src[j2];
        float2 a = *(const float2*)&as[(size_t)s * 2];
        exb0 = __expf(lrelu(a.x + ad0));
        exb1 = __expf(lrelu(a.y + ad1));
    }
    float d0 = exa0 + exb0, d1 = exa1 + exb1;
    for (int j = lo + 128 + lane; j < hi; j += 64) {   // degree > 128 (rare)
        int s = csr_src[j];
        float2 a = *(const float2*)&as[(size_t)s * 2];
        d0 += __expf(lrelu(a.x + ad0));
        d1 += __expf(lrelu(a.y + ad1));
    }
#pragma unroll
    for (int off = 32; off; off >>= 1) {
        d0 += __shfl_xor(d0, off);
        d1 += __shfl_xor(d1, off);
    }
    const float inv = (lane < 32) ? (1.f / d0) : (1.f / d1);
    const bool h0side = (lane < 32);

    float acc0 = 0.f, acc1 = 0.f;
    const int deg = hi - lo;
    const int n1 = deg < 64 ? deg : 64;
    int j = 0;
    for (; j + 8 <= n1; j += 8) {
        int s0 = csr_src[lo + j + 0], s1 = csr_src[lo + j + 1];
        int s2 = csr_src[lo + j + 2], s3 = csr_src[lo + j + 3];
        int s4 = csr_src[lo + j + 4], s5 = csr_src[lo + j + 5];
        int s6 = csr_src[lo + j + 6], s7 = csr_src[lo + j + 7];
        uint u0 = Hb[(size_t)s0 * 64 + lane];
        uint u1 = Hb[(size_t)s1 * 64 + lane];
        uint u2 = Hb[(size_t)s2 * 64 + lane];
        uint u3 = Hb[(size_t)s3 * 64 + lane];
        uint u4 = Hb[(size_t)s4 * 64 + lane];
        uint u5 = Hb[(size_t)s5 * 64 + lane];
        uint u6 = Hb[(size_t)s6 * 64 + lane];
        uint u7 = Hb[(size_t)s7 * 64 + lane];
        float ca0 = __shfl(exa0, j + 0), cb0 = __shfl(exa1, j + 0);
        float ca1 = __shfl(exa0, j + 1), cb1 = __shfl(exa1, j + 1);
        float ca2 = __shfl(exa0, j + 2), cb2 = __shfl(exa1, j + 2);
        float ca3 = __shfl(exa0, j + 3), cb3 = __shfl(exa1, j + 3);
        float ca4 = __shfl(exa0, j + 4), cb4 = __shfl(exa1, j + 4);
        float ca5 = __shfl(exa0, j + 5), cb5 = __shfl(exa1, j + 5);
        float ca6 = __shfl(exa0, j + 6), cb6 = __shfl(exa1, j + 6);
        float ca7 = __shfl(exa0, j + 7), cb7 = __shfl(exa1, j + 7);
        float c0 = h0side ? ca0 : cb0;
        float c1 = h0side ? ca1 : cb1;
        float c2 = h0side ? ca2 : cb2;
        float c3 = h0side ? ca3 : cb3;
        float c4 = h0side ? ca4 : cb4;
        float c5 = h0side ? ca5 : cb5;
        float c6 = h0side ? ca6 : cb6;
        float c7 = h0side ? ca7 : cb7;
        acc0 = fmaf(bf_lo(u0), c0, acc0); acc1 = fmaf(bf_hi(u0), c0, acc1);
        acc0 = fmaf(bf_lo(u1), c1, acc0); acc1 = fmaf(bf_hi(u1), c1, acc1);
        acc0 = fmaf(bf_lo(u2), c2, acc0); acc1 = fmaf(bf_hi(u2), c2, acc1);
        acc0 = fmaf(bf_lo(u3), c3, acc0); acc1 = fmaf(bf_hi(u3), c3, acc1);
        acc0 = fmaf(bf_lo(u4), c4, acc0); acc1 = fmaf(bf_hi(u4), c4, acc1);
        acc0 = fmaf(bf_lo(u5), c5, acc0); acc1 = fmaf(bf_hi(u5), c5, acc1);
        acc0 = fmaf(bf_lo(u6), c6, acc0); acc1 = fmaf(bf_hi(u6), c6, acc1);
        acc0 = fmaf(bf_lo(u7), c7, acc0); acc1 = fmaf(bf_hi(u7), c7, acc1);
    }
    for (; j < n1; j++) {
        int s = csr_src[lo + j];
        float ca = __shfl(exa0, j), cb = __shfl(exa1, j);
        float c = h0side ? ca : cb;
        uint u = Hb[(size_t)s * 64 + lane];
        acc0 = fmaf(bf_lo(u), c, acc0);
        acc1 = fmaf(bf_hi(u), c, acc1);
    }
    if (deg > 64) {
        const int n2 = deg < 128 ? deg : 128;
        for (j = 64; j < n2; j++) {
            int s = csr_src[lo + j];
            float ca = __shfl(exb0, j - 64), cb = __shfl(exb1, j - 64);
            float c = h0side ? ca : cb;
            uint u = Hb[(size_t)s * 64 + lane];
            acc0 = fmaf(bf_lo(u), c, acc0);
            acc1 = fmaf(bf_hi(u), c, acc1);
        }
        for (int jj = lo + 128; jj < hi; jj++) {       // rare; lane-local, no shfl
            int s = csr_src[jj];
            float2 a = *(const float2*)&as[(size_t)s * 2];
            float e0 = __expf(lrelu(a.x + ad0));
            float e1 = __expf(lrelu(a.y + ad1));
            float c = h0side ? e0 : e1;
            uint u = Hb[(size_t)s * 64 + lane];
            acc0 = fmaf(bf_lo(u), c, acc0);
            acc1 = fmaf(bf_hi(u), c, acc1);
        }
    }
    float v0 = acc0 * inv + b[2 * lane];
    float v1 = acc1 * inv + b[2 * lane + 1];
    v0 = v0 > 0.f ? v0 : 0.f;
    v1 = v1 > 0.f ? v1 : 0.f;
    *(float2*)&outp[(size_t)node * 128 + 2 * lane] = make_float2(v0, v1);
}

__global__ void node_agg2_kernel(const int* __restrict__ rowptr, const int* __restrict__ csr_src,
                                 const ushort* __restrict__ Hb,
                                 const float* __restrict__ as, const float* __restrict__ ad,
                                 const float* __restrict__ b, float* __restrict__ outp) {
    int wave = threadIdx.x >> 6;
    int lane = threadIdx.x & 63;
    int node = blockIdx.x * 4 + wave;
    if (node >= N_NODES) return;
    const int lo = rowptr[node], hi = rowptr[node + 1];
    const float adN = ad[node];

    float exa = 0.f, exb = 0.f;
    int j1 = lo + lane;
    if (j1 < hi) exa = __expf(lrelu(as[csr_src[j1]] + adN));
    int j2 = lo + 64 + lane;
    if (j2 < hi) exb = __expf(lrelu(as[csr_src[j2]] + adN));
    float d = exa + exb;
    for (int j = lo + 128 + lane; j < hi; j += 64)
        d += __expf(lrelu(as[csr_src[j]] + adN));
#pragma unroll
    for (int off = 32; off; off >>= 1) d += __shfl_xor(d, off);
    const float inv = 1.f / d;

    float acc = 0.f;
    const int deg = hi - lo;
    const int n1 = deg < 64 ? deg : 64;
    int j = 0;
    for (; j + 8 <= n1; j += 8) {
        int s0 = csr_src[lo + j + 0], s1 = csr_src[lo + j + 1];
        int s2 = csr_src[lo + j + 2], s3 = csr_src[lo + j + 3];
        int s4 = csr_src[lo + j + 4], s5 = csr_src[lo + j + 5];
        int s6 = csr_src[lo + j + 6], s7 = csr_src[lo + j + 7];
        float h0 = __uint_as_float(((uint)Hb[(size_t)s0 * 64 + lane]) << 16);
        float h1 = __uint_as_float(((uint)Hb[(size_t)s1 * 64 + lane]) << 16);
        float h2 = __uint_as_float(((uint)Hb[(size_t)s2 * 64 + lane]) << 16);
        float h3 = __uint_as_float(((uint)Hb[(size_t)s3 * 64 + lane]) << 16);
        float h4 = __uint_as_float(((uint)Hb[(size_t)s4 * 64 + lane]) << 16);
        float h5 = __uint_as_float(((uint)Hb[(size_t)s5 * 64 + lane]) << 16);
        float h6 = __uint_as_float(((uint)Hb[(size_t)s6 * 64 + lane]) << 16);
        float h7 = __uint_as_float(((uint)Hb[(size_t)s7 * 64 + lane]) << 16);
        float c0 = __shfl(exa, j + 0), c1 = __shfl(exa, j + 1);
        float c2 = __shfl(exa, j + 2), c3 = __shfl(exa, j + 3);
        float c4 = __shfl(exa, j + 4), c5 = __shfl(exa, j + 5);
        float c6 = __shfl(exa, j + 6), c7 = __shfl(exa, j + 7);
        acc = fmaf(h0, c0, acc);
        acc = fmaf(h1, c1, acc);
        acc = fmaf(h2, c2, acc);
        acc = fmaf(h3, c3, acc);
        acc = fmaf(h4, c4, acc);
        acc = fmaf(h5, c5, acc);
        acc = fmaf(h6, c6, acc);
        acc = fmaf(h7, c7, acc);
    }
    for (; j < n1; j++) {
        float c = __shfl(exa, j);
        acc = fmaf(__uint_as_float(((uint)Hb[(size_t)csr_src[lo + j] * 64 + lane]) << 16), c, acc);
    }
    if (deg > 64) {
        const int n2 = deg < 128 ? deg : 128;
        for (j = 64; j < n2; j++) {
            float c = __shfl(exb, j - 64);
            acc = fmaf(__uint_as_float(((uint)Hb[(size_t)csr_src[lo + j] * 64 + lane]) << 16), c, acc);
        }
        for (int jj = lo + 128; jj < hi; jj++) {       // rare
            int s = csr_src[jj];
            float c = __expf(lrelu(as[s] + adN));
            acc = fmaf(__uint_as_float(((uint)Hb[(size_t)s * 64 + lane]) << 16), c, acc);
        }
    }
    float v = acc * inv + b[lane];
    outp[(size_t)node * 64 + lane] = v > 0.f ? v : 0.f;
}

// ---------- pool + fc + log_softmax: 4 waves per graph ----------
__global__ void pool_fc_kernel(const float* __restrict__ act2,
                               const int* __restrict__ batch,
                               const float* __restrict__ fcW,
                               const float* __restrict__ fcb,
                               float* __restrict__ out) {
    int g = blockIdx.x;
    int tid = threadIdx.x;            // 256
    int wid = tid >> 6, c = tid & 63;
    __shared__ int slo, shi;
    if (tid == 0) {
        int lo = 0, hi = N_NODES;
        while (lo < hi) { int m = (lo + hi) >> 1; if (batch[m] < g) lo = m + 1; else hi = m; }
        slo = lo;
        lo = 0; hi = N_NODES;
        while (lo < hi) { int m = (lo + hi) >> 1; if (batch[m] < g + 1) lo = m + 1; else hi = m; }
        shi = lo;
    }
    __syncthreads();
    const int lo = slo, hi = shi;
    float sum = 0.f;
    for (int n = lo + wid; n < hi; n += 4) sum += act2[(size_t)n * HID + c];
    __shared__ float ps[4][HID];
    ps[wid][c] = sum;
    __syncthreads();
    if (wid == 0) {
        float t = ps[0][c] + ps[1][c] + ps[2][c] + ps[3][c];
        float cnt = (float)(hi - lo);
        __shared__ float pooled[HID];
        pooled[c] = t / fmaxf(cnt, 1.f);
        __syncthreads();
        __shared__ float ls[OUT_DIM];
        if (c < OUT_DIM) {
            float l = fcb[c];
#pragma unroll 8
            for (int k = 0; k < HID; k++) l = fmaf(pooled[k], fcW[k * OUT_DIM + c], l);
            ls[c] = l;
        }
        __syncthreads();
        if (c < OUT_DIM) {
            float m = fmaxf(ls[0], ls[1]);
            float lse = m + logf(expf(ls[0] - m) + expf(ls[1] - m));
            out[(size_t)g * OUT_DIM + c] = ls[c] - lse;
        }
    }
}

extern "C" void kernel_launch(void* const* d_in, const int* in_sizes, int n_in,
                              void* d_out, int out_size, void* d_ws, size_t ws_size,
                              hipStream_t stream) {
    const float* x    = (const float*)d_in[0];
    const int*   ei   = (const int*)d_in[1];
    const int*   batch= (const int*)d_in[2];
    const float* W1   = (const float*)d_in[3];
    const float* as1w = (const float*)d_in[4];
    const float* ad1w = (const float*)d_in[5];
    const float* b1   = (const float*)d_in[6];
    const float* W2   = (const float*)d_in[7];
    const float* as2w = (const float*)d_in[8];
    const float* ad2w = (const float*)d_in[9];
    const float* b2   = (const float*)d_in[10];
    const float* fcW  = (const float*)d_in[11];
    const float* fcb  = (const float*)d_in[12];

    const size_t N = N_NODES;
    float* ws = (float*)d_ws;
    ushort* h1b  = (ushort*)ws;               // N*128 bf16 = N*64 floats
    float* act1  = ws + N * 64;               // N*128 fp32
    ushort* h2b  = (ushort*)(act1 + N * 128); // N*64 bf16 = N*32 floats
    float* out2  = act1 + N * 128 + N * 32;   // N*64 fp32
    float* alps1 = out2 + N * 64;             // N*2
    float* alpd1 = alps1 + N * 2;             // N*2
    float* alps2 = alpd1 + N * 2;             // N
    float* alpd2 = alps2 + N;                 // N
    int* cnt     = (int*)(alpd2 + N);         // N
    int* rowptr  = cnt + N;                   // N+1
    int* bsum    = rowptr + N + 1;            // NB_SCAN
    int* gcursor = bsum + NB_SCAN;            // NBKT
    int* erank   = gcursor + NBKT;            // EP
    int* csr_src = erank + EP;                // EP
    int2* pairbuf = (int2*)(((uintptr_t)(csr_src + EP) + 7) & ~(uintptr_t)7);  // EP int2

    // ---- fused: layer-1 GEMM+alphas || edge histogram ----
    hipMemsetAsync(cnt, 0, N * sizeof(int), stream);
    fused_gemm1_hist<<<G_GEMM1 + G_HIST, 256, 0, stream>>>(
        x, W1, h1b, as1w, ad1w, alps1, alpd1, ei, cnt, erank);

    // ---- scan (2 kernels; partial also inits gcursor) ----
    partial_kernel<<<NB_SCAN, 256, 0, stream>>>(cnt, bsum, gcursor);
    scanc_kernel<<<NB_SCAN, 256, 0, stream>>>(cnt, bsum, rowptr);

    // ---- bucketed scatter ----
    bucketA_kernel<<<NBKT, 256, 0, stream>>>(ei, rowptr, erank, gcursor, pairbuf);
    bucketB_kernel<<<NBKT, 256, 0, stream>>>(pairbuf, csr_src);

    // ---- layer 1 aggregate ----
    node_agg1_kernel<<<(N + 3) / 4, 256, 0, stream>>>(
        rowptr, csr_src, (const uint*)h1b, alps1, alpd1, b1, act1);

    // ---- layer 2 ----
    gemm_alphas2<<<(N + 7) / 8, 64, 0, stream>>>(
        act1, W2, h2b, as2w, ad2w, alps2, alpd2, (int)N);
    node_agg2_kernel<<<(N + 3) / 4, 256, 0, stream>>>(
        rowptr, csr_src, h2b, alps2, alpd2, b2, out2);

    // ---- pool + fc + log_softmax ----
    pool_fc_kernel<<<N_GRAPHS, 256, 0, stream>>>(out2, batch, fcW, fcb, (float*)d_out);
}